// Round 1
// baseline (955.969 us; speedup 1.0000x reference)
//
#include <hip/hip_runtime.h>

// ---------------------------------------------------------------------------
// 2-layer GCN (PyG GCNConv semantics) + BatchNorm(train stats) + ReLU, fp32.
//   h = X @ W;  out[d] += h[s] * dinv[s]*dinv[d]  (edges + self loops);
//   BN over rows per column; ReLU.  Bias before BN cancels exactly -> skipped.
// ---------------------------------------------------------------------------

#define IN_F 128
#define HID  64
static constexpr float BN_EPS = 1e-5f;

__global__ void fill_ones(float* __restrict__ deg, int n) {
    int i = blockIdx.x * blockDim.x + threadIdx.x;
    if (i < n) deg[i] = 1.0f;   // self-loop contributes 1 to every node's degree
}

__global__ void deg_accum(const int* __restrict__ dst, float* __restrict__ deg, int E) {
    int e = blockIdx.x * blockDim.x + threadIdx.x;
    if (e < E) atomicAdd(&deg[dst[e]], 1.0f);
}

__global__ void make_dinv(float* __restrict__ deg, int n) {
    int i = blockIdx.x * blockDim.x + threadIdx.x;
    if (i < n) deg[i] = rsqrtf(deg[i]);   // deg >= 1 always (self loops)
}

// out[r][c] = sum_k X[r][k] * W[k][HID=64 cols], one thread per output elem.
// blockDim = (64, 4): threadIdx.x = column (coalesced on W), threadIdx.y = row.
template <int K>
__global__ __launch_bounds__(256) void gemm_rowmajor(const float* __restrict__ X,
                                                     const float* __restrict__ W,
                                                     float* __restrict__ out, int n) {
    int c = threadIdx.x;
    int r = blockIdx.x * 4 + threadIdx.y;
    if (r >= n) return;
    const float* xr = X + (size_t)r * K;
    float acc = 0.0f;
#pragma unroll 8
    for (int k = 0; k < K; ++k) acc += xr[k] * W[k * HID + c];
    out[(size_t)r * HID + c] = acc;
}

// agg[i][:] = h[i][:] * dinv[i]^2   (the self-loop term; initializes agg buffer)
__global__ void selfloop_init(const float* __restrict__ h, const float* __restrict__ dinv,
                              float* __restrict__ agg, int n) {
    int i = blockIdx.x * blockDim.x + threadIdx.x;
    if (i < n * HID) {
        int r = i >> 6;
        float dv = dinv[r];
        agg[i] = h[i] * dv * dv;
    }
}

// per edge: agg[dst][c] += h[src][c] * dinv[src]*dinv[dst];  64 lanes = 64 feats
__global__ __launch_bounds__(256) void scatter_edges(const float* __restrict__ h,
                                                     const float* __restrict__ dinv,
                                                     const int* __restrict__ src,
                                                     const int* __restrict__ dst,
                                                     float* __restrict__ agg, int E) {
    int c = threadIdx.x & 63;
    int e = blockIdx.x * (blockDim.x >> 6) + (threadIdx.x >> 6);
    if (e >= E) return;
    int s = src[e];
    int d = dst[e];
    float nrm = dinv[s] * dinv[d];
    atomicAdd(&agg[(size_t)d * HID + c], h[(size_t)s * HID + c] * nrm);
}

// column sums + sums of squares -> stats[0:64] = sum, stats[64:128] = sumsq
__global__ __launch_bounds__(256) void bn_stats(const float* __restrict__ v,
                                                float* __restrict__ stats, int n) {
    int c = threadIdx.x;   // 0..63
    int ry = threadIdx.y;  // 0..3
    float s = 0.0f, s2 = 0.0f;
    for (int r = blockIdx.x * 4 + ry; r < n; r += gridDim.x * 4) {
        float x = v[(size_t)r * HID + c];
        s += x;
        s2 += x * x;
    }
    __shared__ float ls[4][HID];
    __shared__ float ls2[4][HID];
    ls[ry][c] = s;
    ls2[ry][c] = s2;
    __syncthreads();
    if (ry == 0) {
        s  = ls[0][c] + ls[1][c] + ls[2][c] + ls[3][c];
        s2 = ls2[0][c] + ls2[1][c] + ls2[2][c] + ls2[3][c];
        atomicAdd(&stats[c], s);
        atomicAdd(&stats[HID + c], s2);
    }
}

// y = relu((v - m) * g * rsqrt(var + eps) + beta)
__global__ void bn_apply_relu(const float* __restrict__ v, const float* __restrict__ stats,
                              const float* __restrict__ g, const float* __restrict__ beta,
                              float* __restrict__ out, int n) {
    int i = blockIdx.x * blockDim.x + threadIdx.x;
    if (i >= n * HID) return;
    int c = i & 63;
    float inv_n = 1.0f / (float)n;
    float m = stats[c] * inv_n;
    float var = stats[HID + c] * inv_n - m * m;
    float a = g[c] * rsqrtf(var + BN_EPS);
    float y = (v[i] - m) * a + beta[c];
    out[i] = y > 0.0f ? y : 0.0f;
}

extern "C" void kernel_launch(void* const* d_in, const int* in_sizes, int n_in,
                              void* d_out, int out_size, void* d_ws, size_t ws_size,
                              hipStream_t stream) {
    const float* x   = (const float*)d_in[0];
    const int*   ei  = (const int*)d_in[1];
    const float* W1  = (const float*)d_in[2];
    // d_in[3] = b1 (cancels in BN), d_in[4..5] = g1, bt1
    const float* g1  = (const float*)d_in[4];
    const float* bt1 = (const float*)d_in[5];
    const float* W2  = (const float*)d_in[6];
    // d_in[7] = b2 (cancels in BN)
    const float* g2  = (const float*)d_in[8];
    const float* bt2 = (const float*)d_in[9];

    const int n = in_sizes[0] / IN_F;   // 100000
    const int E = in_sizes[1] / 2;      // 1000000
    const int* src = ei;
    const int* dst = ei + E;

    float* ws    = (float*)d_ws;
    float* dinv  = ws;                          // n floats (degree, then rsqrt in place)
    float* bufA  = dinv + n;                    // n*64
    float* bufB  = bufA + (size_t)n * HID;      // n*64
    float* stats = bufB + (size_t)n * HID;      // 256 floats (2 layers x {sum,sumsq})

    hipMemsetAsync(stats, 0, 256 * sizeof(float), stream);

    // degree + dinv
    fill_ones<<<(n + 255) / 256, 256, 0, stream>>>(dinv, n);
    deg_accum<<<(E + 255) / 256, 256, 0, stream>>>(dst, dinv, E);
    make_dinv<<<(n + 255) / 256, 256, 0, stream>>>(dinv, n);

    const int elems = n * HID;
    dim3 gemm_blk(64, 4);

    // ---- layer 1 ----
    gemm_rowmajor<IN_F><<<(n + 3) / 4, gemm_blk, 0, stream>>>(x, W1, bufA, n);
    selfloop_init<<<(elems + 255) / 256, 256, 0, stream>>>(bufA, dinv, bufB, n);
    scatter_edges<<<(E + 3) / 4, 256, 0, stream>>>(bufA, dinv, src, dst, bufB, E);
    bn_stats<<<256, gemm_blk, 0, stream>>>(bufB, stats, n);
    bn_apply_relu<<<(elems + 255) / 256, 256, 0, stream>>>(bufB, stats, g1, bt1, bufA, n);

    // ---- layer 2 ----
    gemm_rowmajor<HID><<<(n + 3) / 4, gemm_blk, 0, stream>>>(bufA, W2, bufB, n);
    selfloop_init<<<(elems + 255) / 256, 256, 0, stream>>>(bufB, dinv, bufA, n);
    scatter_edges<<<(E + 3) / 4, 256, 0, stream>>>(bufB, dinv, src, dst, bufA, E);
    bn_stats<<<256, gemm_blk, 0, stream>>>(bufA, stats + 128, n);
    bn_apply_relu<<<(elems + 255) / 256, 256, 0, stream>>>(bufA, stats + 128, g2, bt2,
                                                           (float*)d_out, n);
}

// Round 2
// 825.200 us; speedup vs baseline: 1.1585x; 1.1585x over previous
//
#include <hip/hip_runtime.h>

// ---------------------------------------------------------------------------
// 2-layer GCN + BN(train stats) + ReLU, fp32.
// R2: CSR-gather aggregation (no fp32 atomics on features), BN-stats fused
// into aggregation, BN1-apply+ReLU fused into GEMM2.
// Bias before BN cancels exactly -> skipped.
// ---------------------------------------------------------------------------

#define IN_F 128
#define HID  64
#define SCAN_CHUNK 512
static constexpr float BN_EPS = 1e-5f;

// ---- CSR build ------------------------------------------------------------

__global__ void count_dst(const int* __restrict__ dst, int* __restrict__ counts, int E) {
    int e = blockIdx.x * blockDim.x + threadIdx.x;
    if (e < E) atomicAdd(&counts[dst[e]], 1);
}

// per-block totals of 512-element chunks
__global__ void scan_block_reduce(const int* __restrict__ counts, int* __restrict__ blockSums, int n) {
    __shared__ int red[256];
    int base = blockIdx.x * SCAN_CHUNK;
    int t = threadIdx.x;
    int i0 = base + 2 * t, i1 = i0 + 1;
    int v = 0;
    if (i0 < n) v += counts[i0];
    if (i1 < n) v += counts[i1];
    red[t] = v;
    __syncthreads();
    for (int st = 128; st > 0; st >>= 1) {
        if (t < st) red[t] += red[t + st];
        __syncthreads();
    }
    if (t == 0) blockSums[blockIdx.x] = red[0];
}

// exclusive scan of <=256 block sums (B = ceil(100000/512) = 196)
__global__ void scan_top(const int* __restrict__ blockSums, int* __restrict__ blockOffs, int B) {
    __shared__ int a[2][256];
    int t = threadIdx.x;
    int v = (t < B) ? blockSums[t] : 0;
    int pin = 0;
    a[0][t] = v;
    __syncthreads();
    for (int st = 1; st < 256; st <<= 1) {
        int x = a[pin][t];
        if (t >= st) x += a[pin][t - st];
        a[pin ^ 1][t] = x;
        pin ^= 1;
        __syncthreads();
    }
    if (t < B) blockOffs[t] = a[pin][t] - v;  // exclusive
}

// exclusive scan within chunk + blockOff -> ptr, cursor; dinv = rsqrt(deg+1)
__global__ void scan_write(const int* __restrict__ counts, const int* __restrict__ blockOffs,
                           int* __restrict__ ptr, int* __restrict__ cursor,
                           float* __restrict__ dinv, int n) {
    __shared__ int a[2][256];
    int base = blockIdx.x * SCAN_CHUNK;
    int t = threadIdx.x;
    int i0 = base + 2 * t, i1 = i0 + 1;
    int c0 = (i0 < n) ? counts[i0] : 0;
    int c1 = (i1 < n) ? counts[i1] : 0;
    int s = c0 + c1;
    int pin = 0;
    a[0][t] = s;
    __syncthreads();
    for (int st = 1; st < 256; st <<= 1) {
        int x = a[pin][t];
        if (t >= st) x += a[pin][t - st];
        a[pin ^ 1][t] = x;
        pin ^= 1;
        __syncthreads();
    }
    int excl = a[pin][t] - s + blockOffs[blockIdx.x];
    if (i0 < n) {
        ptr[i0] = excl; cursor[i0] = excl;
        dinv[i0] = rsqrtf((float)c0 + 1.0f);
    }
    if (i1 < n) {
        ptr[i1] = excl + c0; cursor[i1] = excl + c0;
        dinv[i1] = rsqrtf((float)c1 + 1.0f);
    }
}

__global__ void fill_csr(const int* __restrict__ src, const int* __restrict__ dst,
                         int* __restrict__ cursor, int* __restrict__ csr, int E) {
    int e = blockIdx.x * blockDim.x + threadIdx.x;
    if (e < E) {
        int pos = atomicAdd(&cursor[dst[e]], 1);
        csr[pos] = src[e];
    }
}

// ---- dense compute --------------------------------------------------------

// out[r][c] = sum_k X[r][k] * W[k][64], one wave per row, lane = column.
template <int K>
__global__ __launch_bounds__(256) void gemm_rowmajor(const float* __restrict__ X,
                                                     const float* __restrict__ W,
                                                     float* __restrict__ out, int n) {
    int c = threadIdx.x;
    int r = blockIdx.x * 4 + threadIdx.y;
    if (r >= n) return;
    const float* xr = X + (size_t)r * K;
    float acc = 0.0f;
#pragma unroll 8
    for (int k = 0; k < K; ++k) acc += xr[k] * W[k * HID + c];
    out[(size_t)r * HID + c] = acc;
}

// per node i: agg[i][c] = (h[i][c]*dinv[i] + sum_{s in N(i)} h[s][c]*dinv[s]) * dinv[i]
// + per-column BN partial sums (block-reduced, atomics to stats).
__global__ __launch_bounds__(256) void aggregate_stats(
    const float* __restrict__ h, const float* __restrict__ dinv,
    const int* __restrict__ ptr, const int* __restrict__ counts,
    const int* __restrict__ csr, float* __restrict__ agg,
    float* __restrict__ stats, int n) {
    int c = threadIdx.x & 63;
    int wid = threadIdx.x >> 6;          // 0..3
    int gw = blockIdx.x * 4 + wid;
    int nw = gridDim.x * 4;
    float s = 0.0f, s2 = 0.0f;
    for (int i = gw; i < n; i += nw) {
        float di = dinv[i];
        float acc = h[(size_t)i * HID + c] * di;   // self loop (dinv^2 via final *di)
        int b = ptr[i], cnt = counts[i];
        for (int k = 0; k < cnt; ++k) {
            int sI = csr[b + k];                    // wave-uniform
            acc += h[(size_t)sI * HID + c] * dinv[sI];
        }
        float out = acc * di;
        agg[(size_t)i * HID + c] = out;
        s += out;
        s2 += out * out;
    }
    __shared__ float ls[4][HID];
    __shared__ float ls2[4][HID];
    ls[wid][c] = s;
    ls2[wid][c] = s2;
    __syncthreads();
    if (wid == 0) {
        float ts = ls[0][c] + ls[1][c] + ls[2][c] + ls[3][c];
        float t2 = ls2[0][c] + ls2[1][c] + ls2[2][c] + ls2[3][c];
        atomicAdd(&stats[c], ts);
        atomicAdd(&stats[HID + c], t2);
    }
}

// out[r][c] = sum_k relu(bn(v[r][k])) * W[k][c]   (BN1 apply fused into GEMM2)
__global__ __launch_bounds__(256) void bn_gemm64(
    const float* __restrict__ v, const float* __restrict__ stats,
    const float* __restrict__ g, const float* __restrict__ beta,
    const float* __restrict__ W, float* __restrict__ out, int n) {
    __shared__ float Wl[HID * HID];
    __shared__ float m_s[HID], a_s[HID], b_s[HID];
    int t = threadIdx.x;
    for (int i = t; i < HID * HID; i += 256) Wl[i] = W[i];
    if (t < HID) {
        float inv_n = 1.0f / (float)n;
        float mm = stats[t] * inv_n;
        float var = stats[HID + t] * inv_n - mm * mm;
        m_s[t] = mm;
        a_s[t] = g[t] * rsqrtf(var + BN_EPS);
        b_s[t] = beta[t];
    }
    __syncthreads();
    int c = t & 63, wid = t >> 6;
    int gw = blockIdx.x * 4 + wid, nw = gridDim.x * 4;
    for (int r = gw; r < n; r += nw) {
        const float* row = v + (size_t)r * HID;
        float acc = 0.0f;
#pragma unroll 8
        for (int k = 0; k < HID; ++k) {
            float xv = row[k];                      // wave-uniform, L1-hot
            float hv = (xv - m_s[k]) * a_s[k] + b_s[k];
            hv = hv > 0.0f ? hv : 0.0f;
            acc += hv * Wl[k * HID + c];
        }
        out[(size_t)r * HID + c] = acc;
    }
}

// final BN+ReLU (layer 2) -> d_out
__global__ void bn_apply_relu(const float* __restrict__ v, const float* __restrict__ stats,
                              const float* __restrict__ g, const float* __restrict__ beta,
                              float* __restrict__ out, int n) {
    int i = blockIdx.x * blockDim.x + threadIdx.x;
    if (i >= n * HID) return;
    int c = i & 63;
    float inv_n = 1.0f / (float)n;
    float m = stats[c] * inv_n;
    float var = stats[HID + c] * inv_n - m * m;
    float a = g[c] * rsqrtf(var + BN_EPS);
    float y = (v[i] - m) * a + beta[c];
    out[i] = y > 0.0f ? y : 0.0f;
}

// ---------------------------------------------------------------------------

extern "C" void kernel_launch(void* const* d_in, const int* in_sizes, int n_in,
                              void* d_out, int out_size, void* d_ws, size_t ws_size,
                              hipStream_t stream) {
    const float* x   = (const float*)d_in[0];
    const int*   ei  = (const int*)d_in[1];
    const float* W1  = (const float*)d_in[2];
    const float* g1  = (const float*)d_in[4];
    const float* bt1 = (const float*)d_in[5];
    const float* W2  = (const float*)d_in[6];
    const float* g2  = (const float*)d_in[8];
    const float* bt2 = (const float*)d_in[9];

    const int n = in_sizes[0] / IN_F;   // 100000
    const int E = in_sizes[1] / 2;      // 1000000
    const int* src = ei;
    const int* dst = ei + E;

    // ws layout (all 16B-aligned: n, E multiples of 4)
    char* w = (char*)d_ws;
    int*   counts    = (int*)w;                 w += (size_t)n * 4;
    int*   ptr       = (int*)w;                 w += (size_t)n * 4;
    int*   cursor    = (int*)w;                 w += (size_t)n * 4;
    float* dinv      = (float*)w;               w += (size_t)n * 4;
    int*   blockSums = (int*)w;                 w += 256 * 4;
    int*   blockOffs = (int*)w;                 w += 256 * 4;
    float* stats     = (float*)w;               w += 256 * 4;   // 2 layers x {sum,sumsq}
    int*   csr       = (int*)w;                 w += (size_t)E * 4;
    float* bufA      = (float*)w;               w += (size_t)n * HID * 4;
    float* bufB      = (float*)w;               // n*HID*4

    hipMemsetAsync(counts, 0, (size_t)n * 4, stream);
    hipMemsetAsync(stats, 0, 256 * 4, stream);

    const int B = (n + SCAN_CHUNK - 1) / SCAN_CHUNK;   // 196 <= 256

    count_dst<<<(E + 255) / 256, 256, 0, stream>>>(dst, counts, E);
    scan_block_reduce<<<B, 256, 0, stream>>>(counts, blockSums, n);
    scan_top<<<1, 256, 0, stream>>>(blockSums, blockOffs, B);
    scan_write<<<B, 256, 0, stream>>>(counts, blockOffs, ptr, cursor, dinv, n);
    fill_csr<<<(E + 255) / 256, 256, 0, stream>>>(src, dst, cursor, csr, E);

    dim3 gemm_blk(64, 4);

    // ---- layer 1 ----
    gemm_rowmajor<IN_F><<<(n + 3) / 4, gemm_blk, 0, stream>>>(x, W1, bufA, n);
    aggregate_stats<<<1024, 256, 0, stream>>>(bufA, dinv, ptr, counts, csr, bufB, stats, n);

    // ---- layer 2 (BN1+ReLU fused into GEMM2 read) ----
    bn_gemm64<<<2048, 256, 0, stream>>>(bufB, stats, g1, bt1, W2, bufA, n);
    aggregate_stats<<<1024, 256, 0, stream>>>(bufA, dinv, ptr, counts, csr, bufB, stats + 128, n);
    bn_apply_relu<<<((size_t)n * HID + 255) / 256, 256, 0, stream>>>(bufB, stats + 128, g2, bt2,
                                                                     (float*)d_out, n);
}